// Round 3
// baseline (484.234 us; speedup 1.0000x reference)
//
#include <hip/hip_runtime.h>
#include <hip/hip_bf16.h>

// Graph mean aggregation via coarse dst-bucketing (no per-node CSR, no float
// global atomics, no fine-grained random global writes):
//   bucket = dst >> SHIFT  (NPB=128 nodes per bucket)
//   1) hist_kernel:   LDS histogram of buckets -> global bucket_cnt
//   2) scan_bins:     exclusive scan over nb bins (single block)
//   3) pack_scatter:  per-block LDS histogram + chunk reservation; write
//                     packed (local_dst<<17 | src) into per-bucket regions
//   4) aggregate:     one block per bucket; acc[128][32] + deg in LDS;
//                     stream packed edges, gather h rows, LDS atomics,
//                     coalesced normalized output write

#define D_FEAT 32
#define NPB 128          // nodes per bucket
#define SHIFT 7          // log2(NPB)
#define PACK_GRID 256

__global__ void zero_i32_kernel(int* __restrict__ p, int n) {
    for (int i = blockIdx.x * blockDim.x + threadIdx.x; i < n;
         i += gridDim.x * blockDim.x) p[i] = 0;
}

__global__ void hist_kernel(const int* __restrict__ dst, int n_edges,
                            int* __restrict__ bucket_cnt, int nb) {
    extern __shared__ int lbin[];   // nb ints
    for (int i = threadIdx.x; i < nb; i += blockDim.x) lbin[i] = 0;
    __syncthreads();
    for (int i = blockIdx.x * blockDim.x + threadIdx.x; i < n_edges;
         i += gridDim.x * blockDim.x)
        atomicAdd(&lbin[dst[i] >> SHIFT], 1);
    __syncthreads();
    for (int i = threadIdx.x; i < nb; i += blockDim.x)
        if (lbin[i]) atomicAdd(&bucket_cnt[i], lbin[i]);
}

// single block, 1024 threads, nb <= 1024
__global__ void scan_bins_kernel(const int* __restrict__ cnt,
                                 int* __restrict__ off,
                                 int* __restrict__ cur, int nb) {
    __shared__ int tmp[1024];
    int t = threadIdx.x;
    int orig = (t < nb) ? cnt[t] : 0;
    int v = orig;
    for (int o = 1; o < 1024; o <<= 1) {
        tmp[t] = v;
        __syncthreads();
        if (t >= o) v += tmp[t - o];
        __syncthreads();
    }
    if (t < nb) {
        off[t] = v - orig;          // exclusive
        cur[t] = v - orig;
        if (t == nb - 1) off[nb] = v;
    }
}

__global__ void pack_scatter_kernel(const int* __restrict__ src,
                                    const int* __restrict__ dst, int n_edges,
                                    int* __restrict__ bucket_cur,
                                    int* __restrict__ packed, int nb, int epb) {
    extern __shared__ int sh[];     // 2*nb ints
    int* lcnt = sh;
    int* lcur = sh + nb;
    int lo = blockIdx.x * epb;
    int hi = min(lo + epb, n_edges);
    for (int i = threadIdx.x; i < nb; i += blockDim.x) lcnt[i] = 0;
    __syncthreads();
    for (int i = lo + threadIdx.x; i < hi; i += blockDim.x)
        atomicAdd(&lcnt[dst[i] >> SHIFT], 1);
    __syncthreads();
    for (int i = threadIdx.x; i < nb; i += blockDim.x) {
        int c = lcnt[i];
        lcur[i] = c ? atomicAdd(&bucket_cur[i], c) : 0;
    }
    __syncthreads();
    for (int i = lo + threadIdx.x; i < hi; i += blockDim.x) {
        int dd = dst[i];
        int b = dd >> SHIFT;
        int pos = atomicAdd(&lcur[b], 1);
        packed[pos] = ((dd & (NPB - 1)) << 17) | src[i];
    }
}

__global__ __launch_bounds__(256) void aggregate_kernel(
        const float* __restrict__ h, const int* __restrict__ packed,
        const int* __restrict__ off, float* __restrict__ out, int n_nodes) {
    __shared__ float acc[NPB * D_FEAT];   // 16 KB
    __shared__ int degi[NPB];
    int b = blockIdx.x;
    for (int i = threadIdx.x; i < NPB * D_FEAT; i += 256) acc[i] = 0.0f;
    for (int i = threadIdx.x; i < NPB; i += 256) degi[i] = 0;
    __syncthreads();

    int beg = off[b], end = off[b + 1];
    int lane = threadIdx.x & 63;
    int wid  = threadIdx.x >> 6;       // 4 waves
    int half = lane >> 5;              // each half-wave owns one edge
    int d    = lane & 31;
    for (int j = beg + wid * 2 + half; j < end; j += 8) {
        int p  = packed[j];
        int s  = p & 0x1FFFF;
        int ld = p >> 17;
        float v = h[(size_t)s * D_FEAT + d];
        atomicAdd(&acc[ld * D_FEAT + d], v);
        if (d == 0) atomicAdd(&degi[ld], 1);
    }
    __syncthreads();

    size_t obase = (size_t)b * NPB * D_FEAT;
    for (int i = threadIdx.x; i < NPB * D_FEAT; i += 256) {
        int node = b * NPB + (i >> 5);
        if (node < n_nodes)
            out[obase + i] = acc[i] / fmaxf((float)degi[i >> 5], 1.0f);
    }
}

// ---------------- fallback (round-1 atomic path) if ws too small -------------
__global__ void zero_init_kernel(float* __restrict__ out, int out_n,
                                 float* __restrict__ deg, int n_nodes) {
    int total = out_n + n_nodes;
    for (int i = blockIdx.x * blockDim.x + threadIdx.x; i < total;
         i += gridDim.x * blockDim.x) {
        if (i < out_n) out[i] = 0.0f;
        else deg[i - out_n] = 0.0f;
    }
}
__global__ void scatter_kernel(const float* __restrict__ h,
                               const int* __restrict__ src,
                               const int* __restrict__ dst,
                               float* __restrict__ out,
                               float* __restrict__ deg, int n_edges) {
    long long tid = (long long)blockIdx.x * blockDim.x + threadIdx.x;
    long long total = (long long)n_edges * D_FEAT;
    if (tid >= total) return;
    int e = (int)(tid >> 5);
    int d = (int)(tid & 31);
    float v = h[(long long)src[e] * D_FEAT + d];
    atomicAdd(&out[(long long)dst[e] * D_FEAT + d], v);
    if (d == 0) atomicAdd(&deg[dst[e]], 1.0f);
}
__global__ void finalize_kernel(float* __restrict__ out,
                                const float* __restrict__ deg, int n_nodes) {
    int total = n_nodes * D_FEAT;
    for (int i = blockIdx.x * blockDim.x + threadIdx.x; i < total;
         i += gridDim.x * blockDim.x)
        out[i] = out[i] / fmaxf(deg[i >> 5], 1.0f);
}
// -----------------------------------------------------------------------------

extern "C" void kernel_launch(void* const* d_in, const int* in_sizes, int n_in,
                              void* d_out, int out_size, void* d_ws, size_t ws_size,
                              hipStream_t stream) {
    const float* h = (const float*)d_in[0];
    const int* src = (const int*)d_in[1];
    const int* dst = (const int*)d_in[2];
    float* out = (float*)d_out;

    int n_nodes = in_sizes[0] / D_FEAT;
    int n_edges = in_sizes[1];
    int nb = (n_nodes + NPB - 1) >> SHIFT;   // 782 for N=100K

    size_t need = ((size_t)3 * nb + 1 + (size_t)n_edges) * sizeof(int);
    if (ws_size < need || nb > 1024) {
        // fallback: atomic scatter path (needs n_nodes floats)
        float* deg = (float*)d_ws;
        int total0 = n_nodes * D_FEAT + n_nodes;
        zero_init_kernel<<<min((total0 + 255) / 256, 2048), 256, 0, stream>>>(
            out, n_nodes * D_FEAT, deg, n_nodes);
        long long total = (long long)n_edges * D_FEAT;
        scatter_kernel<<<(int)((total + 255) / 256), 256, 0, stream>>>(
            h, src, dst, out, deg, n_edges);
        finalize_kernel<<<min((n_nodes * D_FEAT + 255) / 256, 2048), 256, 0,
                          stream>>>(out, deg, n_nodes);
        return;
    }

    int* wsI        = (int*)d_ws;
    int* bucket_cnt = wsI;                   // nb
    int* bucket_off = bucket_cnt + nb;       // nb + 1
    int* bucket_cur = bucket_off + nb + 1;   // nb
    int* packed     = bucket_cur + nb;       // n_edges

    zero_i32_kernel<<<4, 256, 0, stream>>>(bucket_cnt, nb);
    hist_kernel<<<256, 256, nb * sizeof(int), stream>>>(dst, n_edges, bucket_cnt, nb);
    scan_bins_kernel<<<1, 1024, 0, stream>>>(bucket_cnt, bucket_off, bucket_cur, nb);
    int epb = (n_edges + PACK_GRID - 1) / PACK_GRID;
    pack_scatter_kernel<<<PACK_GRID, 256, 2 * nb * sizeof(int), stream>>>(
        src, dst, n_edges, bucket_cur, packed, nb, epb);
    aggregate_kernel<<<nb, 256, 0, stream>>>(h, packed, bucket_off, out, n_nodes);
}

// Round 4
// 407.630 us; speedup vs baseline: 1.1879x; 1.1879x over previous
//
#include <hip/hip_runtime.h>
#include <hip/hip_bf16.h>

// Graph mean aggregation via coarse dst-bucketing.
//   bucket = dst >> SHIFT  (NPB=128 nodes per bucket)
//   1) hist:        LDS histogram of buckets -> global bucket_cnt
//   2) scan_bins:   exclusive scan over nb bins (single block)
//   3) pack_scatter: 64 big blocks; per-(block,bin) chunk reservation; packed
//                    (local_dst<<17 | src) written in ~128B single-owner chunks
//   4) aggregate:   SPLIT blocks per bucket, float4 gather (8 lanes/edge),
//                   LDS acc [128][33] (padded), coalesced atomic merge to out
//   5) finalize:    out /= max(deg,1)

#define D_FEAT 32
#define NPB 128
#define SHIFT 7
#define SPLIT 4
#define PACK_GRID 64
#define PACK_BLOCK 1024

__global__ void zero_i32_kernel(int* __restrict__ p, int n) {
    for (int i = blockIdx.x * blockDim.x + threadIdx.x; i < n;
         i += gridDim.x * blockDim.x) p[i] = 0;
}

__global__ void zero_out_kernel(float* __restrict__ out, int out_n,
                                int* __restrict__ deg, int n_nodes) {
    int total = out_n + n_nodes;
    for (int i = blockIdx.x * blockDim.x + threadIdx.x; i < total;
         i += gridDim.x * blockDim.x) {
        if (i < out_n) out[i] = 0.0f;
        else deg[i - out_n] = 0;
    }
}

__global__ void hist_kernel(const int* __restrict__ dst, int n_edges,
                            int* __restrict__ bucket_cnt, int nb) {
    extern __shared__ int lbin[];
    for (int i = threadIdx.x; i < nb; i += blockDim.x) lbin[i] = 0;
    __syncthreads();
    for (int i = blockIdx.x * blockDim.x + threadIdx.x; i < n_edges;
         i += gridDim.x * blockDim.x)
        atomicAdd(&lbin[dst[i] >> SHIFT], 1);
    __syncthreads();
    for (int i = threadIdx.x; i < nb; i += blockDim.x)
        if (lbin[i]) atomicAdd(&bucket_cnt[i], lbin[i]);
}

__global__ void scan_bins_kernel(const int* __restrict__ cnt,
                                 int* __restrict__ off,
                                 int* __restrict__ cur, int nb) {
    __shared__ int tmp[1024];
    int t = threadIdx.x;
    int orig = (t < nb) ? cnt[t] : 0;
    int v = orig;
    for (int o = 1; o < 1024; o <<= 1) {
        tmp[t] = v;
        __syncthreads();
        if (t >= o) v += tmp[t - o];
        __syncthreads();
    }
    if (t < nb) {
        off[t] = v - orig;
        cur[t] = v - orig;
        if (t == nb - 1) off[nb] = v;
    }
}

__global__ __launch_bounds__(PACK_BLOCK) void pack_scatter_kernel(
        const int* __restrict__ src, const int* __restrict__ dst, int n_edges,
        int* __restrict__ bucket_cur, int* __restrict__ packed,
        int nb, int epb) {
    extern __shared__ int sh[];     // 2*nb ints
    int* lcnt = sh;
    int* lcur = sh + nb;
    int lo = blockIdx.x * epb;
    int hi = min(lo + epb, n_edges);
    for (int i = threadIdx.x; i < nb; i += blockDim.x) lcnt[i] = 0;
    __syncthreads();
    for (int i = lo + threadIdx.x; i < hi; i += blockDim.x)
        atomicAdd(&lcnt[dst[i] >> SHIFT], 1);
    __syncthreads();
    for (int i = threadIdx.x; i < nb; i += blockDim.x) {
        int c = lcnt[i];
        lcur[i] = c ? atomicAdd(&bucket_cur[i], c) : 0;
    }
    __syncthreads();
    for (int i = lo + threadIdx.x; i < hi; i += blockDim.x) {
        int dd = dst[i];
        int b = dd >> SHIFT;
        int pos = atomicAdd(&lcur[b], 1);
        packed[pos] = ((dd & (NPB - 1)) << 17) | src[i];
    }
}

__global__ __launch_bounds__(256) void aggregate_kernel(
        const float4* __restrict__ h4, const int* __restrict__ packed,
        const int* __restrict__ off, float* __restrict__ out,
        int* __restrict__ deg, int n_nodes) {
    __shared__ float acc[NPB * 33];   // padded: conflict-free merge reads
    __shared__ int degi[NPB];
    int b = blockIdx.x / SPLIT;
    int c = blockIdx.x % SPLIT;
    for (int i = threadIdx.x; i < NPB * 33; i += 256) acc[i] = 0.0f;
    for (int i = threadIdx.x; i < NPB; i += 256) degi[i] = 0;
    __syncthreads();

    int beg = off[b], end = off[b + 1];
    int len = end - beg;
    int per = (len + SPLIT - 1) / SPLIT;
    int lo = beg + c * per;
    int hi = min(lo + per, end);

    int g = threadIdx.x >> 3;   // edge slot 0..31 (32 edges in flight/block)
    int q = threadIdx.x & 7;    // float4 quarter-row
    for (int j = lo + g; j < hi; j += 32) {
        int p  = packed[j];
        int s  = p & 0x1FFFF;
        int ld = p >> 17;
        float4 v = h4[(size_t)s * 8 + q];
        int base = ld * 33 + q * 4;
        atomicAdd(&acc[base + 0], v.x);
        atomicAdd(&acc[base + 1], v.y);
        atomicAdd(&acc[base + 2], v.z);
        atomicAdd(&acc[base + 3], v.w);
        if (q == 0) atomicAdd(&degi[ld], 1);
    }
    __syncthreads();

    int nodebase = b * NPB;
    for (int i = threadIdx.x; i < NPB * D_FEAT; i += 256) {
        int ln = i >> 5, d = i & 31;
        int node = nodebase + ln;
        if (node < n_nodes) {
            float v = acc[ln * 33 + d];
            if (v != 0.0f) atomicAdd(&out[(size_t)node * D_FEAT + d], v);
        }
    }
    for (int i = threadIdx.x; i < NPB; i += 256) {
        int node = nodebase + i;
        if (node < n_nodes && degi[i]) atomicAdd(&deg[node], degi[i]);
    }
}

__global__ void finalize_kernel(float* __restrict__ out,
                                const int* __restrict__ deg, int n_nodes) {
    int total = n_nodes * D_FEAT;
    for (int i = blockIdx.x * blockDim.x + threadIdx.x; i < total;
         i += gridDim.x * blockDim.x)
        out[i] = out[i] / fmaxf((float)deg[i >> 5], 1.0f);
}

// ---------------- fallback (round-1 atomic path) if ws too small -------------
__global__ void zero_init_fb(float* __restrict__ out, int out_n,
                             float* __restrict__ deg, int n_nodes) {
    int total = out_n + n_nodes;
    for (int i = blockIdx.x * blockDim.x + threadIdx.x; i < total;
         i += gridDim.x * blockDim.x) {
        if (i < out_n) out[i] = 0.0f;
        else deg[i - out_n] = 0.0f;
    }
}
__global__ void scatter_fb(const float* __restrict__ h,
                           const int* __restrict__ src,
                           const int* __restrict__ dst,
                           float* __restrict__ out,
                           float* __restrict__ deg, int n_edges) {
    long long tid = (long long)blockIdx.x * blockDim.x + threadIdx.x;
    long long total = (long long)n_edges * D_FEAT;
    if (tid >= total) return;
    int e = (int)(tid >> 5);
    int d = (int)(tid & 31);
    float v = h[(long long)src[e] * D_FEAT + d];
    atomicAdd(&out[(long long)dst[e] * D_FEAT + d], v);
    if (d == 0) atomicAdd(&deg[dst[e]], 1.0f);
}
__global__ void finalize_fb(float* __restrict__ out,
                            const float* __restrict__ deg, int n_nodes) {
    int total = n_nodes * D_FEAT;
    for (int i = blockIdx.x * blockDim.x + threadIdx.x; i < total;
         i += gridDim.x * blockDim.x)
        out[i] = out[i] / fmaxf(deg[i >> 5], 1.0f);
}
// -----------------------------------------------------------------------------

extern "C" void kernel_launch(void* const* d_in, const int* in_sizes, int n_in,
                              void* d_out, int out_size, void* d_ws, size_t ws_size,
                              hipStream_t stream) {
    const float* h = (const float*)d_in[0];
    const int* src = (const int*)d_in[1];
    const int* dst = (const int*)d_in[2];
    float* out = (float*)d_out;

    int n_nodes = in_sizes[0] / D_FEAT;
    int n_edges = in_sizes[1];
    int nb = (n_nodes + NPB - 1) >> SHIFT;

    size_t need = ((size_t)3 * nb + 1 + (size_t)n_nodes + (size_t)n_edges) * sizeof(int);
    if (ws_size < need || nb > 1024 || n_nodes > 131072) {
        float* deg = (float*)d_ws;
        int total0 = n_nodes * D_FEAT + n_nodes;
        zero_init_fb<<<min((total0 + 255) / 256, 2048), 256, 0, stream>>>(
            out, n_nodes * D_FEAT, deg, n_nodes);
        long long total = (long long)n_edges * D_FEAT;
        scatter_fb<<<(int)((total + 255) / 256), 256, 0, stream>>>(
            h, src, dst, out, deg, n_edges);
        finalize_fb<<<min((n_nodes * D_FEAT + 255) / 256, 2048), 256, 0,
                      stream>>>(out, deg, n_nodes);
        return;
    }

    int* wsI        = (int*)d_ws;
    int* bucket_cnt = wsI;                   // nb
    int* bucket_off = bucket_cnt + nb;       // nb + 1
    int* bucket_cur = bucket_off + nb + 1;   // nb
    int* deg        = bucket_cur + nb;       // n_nodes
    int* packed     = deg + n_nodes;         // n_edges

    zero_i32_kernel<<<4, 256, 0, stream>>>(bucket_cnt, nb);
    zero_out_kernel<<<2048, 256, 0, stream>>>(out, n_nodes * D_FEAT, deg, n_nodes);
    hist_kernel<<<256, 256, nb * sizeof(int), stream>>>(dst, n_edges, bucket_cnt, nb);
    scan_bins_kernel<<<1, 1024, 0, stream>>>(bucket_cnt, bucket_off, bucket_cur, nb);
    int epb = (n_edges + PACK_GRID - 1) / PACK_GRID;
    pack_scatter_kernel<<<PACK_GRID, PACK_BLOCK, 2 * nb * sizeof(int), stream>>>(
        src, dst, n_edges, bucket_cur, packed, nb, epb);
    aggregate_kernel<<<nb * SPLIT, 256, 0, stream>>>(
        (const float4*)h, packed, bucket_off, out, deg, n_nodes);
    finalize_kernel<<<2048, 256, 0, stream>>>(out, deg, n_nodes);
}